// Round 1
// baseline (3455.746 us; speedup 1.0000x reference)
//
#include <hip/hip_runtime.h>

constexpr int NN = 50000;   // nodes
constexpr int KD = 128;     // feature dim (GEMM K, and Fin/Fh)
constexpr int RR = 8;       // relations

#define F4(p)  (*(float4*)(p))
#define F4C(p) (*(const float4*)(p))

// ---------------- GEMM: C[M,N] (+)= (rowscale) * A[M,128] @ B[128,N] (+ bias) ----
// BM=64, BN=64, BK=32, 256 threads, 4x4 register tile per thread.
// ACC=false: C = A@B + bias (bias_or_scale = bias[N])
// ACC=true : C += bias_or_scale[row] * (A@B)   (bias_or_scale = rowscale[M])
template<bool ACC>
__global__ __launch_bounds__(256)
void gemm_k128(const float* __restrict__ A, const float* __restrict__ B,
               float* __restrict__ C, const float* __restrict__ bias_or_scale,
               int M, int N) {
  __shared__ float As[64][36];   // stride 36 floats: 16B-aligned rows, 2-way-max banks
  __shared__ float Bs[32][64];
  const int t = threadIdx.x;
  const int row0 = blockIdx.x * 64;
  const int col0 = blockIdx.y * 64;

  const int cg = t & 15, rg = t >> 4;
  const int r0 = rg * 4, c0 = cg * 4;

  float acc[4][4] = {};

  for (int kt = 0; kt < 4; ++kt) {
    __syncthreads();
    // stage A tile: 64 rows x 32 k's
    {
      const int c4 = (t & 7) * 4;
      const int rr = t >> 3;          // 0..31
#pragma unroll
      for (int hh = 0; hh < 2; ++hh) {
        const int r = rr + hh * 32;
        const int gr = row0 + r;
        float4 v = make_float4(0.f, 0.f, 0.f, 0.f);
        if (gr < M) v = F4C(&A[(long)gr * KD + kt * 32 + c4]);
        As[r][c4 + 0] = v.x; As[r][c4 + 1] = v.y;
        As[r][c4 + 2] = v.z; As[r][c4 + 3] = v.w;
      }
    }
    // stage B tile: 32 k's x 64 cols
    {
      const int c4 = (t & 15) * 4;
      const int kr = t >> 4;          // 0..15
#pragma unroll
      for (int hh = 0; hh < 2; ++hh) {
        const int k = kr + hh * 16;
        F4(&Bs[k][c4]) = F4C(&B[(long)(kt * 32 + k) * N + col0 + c4]);
      }
    }
    __syncthreads();
#pragma unroll
    for (int k4 = 0; k4 < 8; ++k4) {
      float a[4][4], b[4][4];
#pragma unroll
      for (int i = 0; i < 4; ++i) F4(&a[i][0]) = F4(&As[r0 + i][k4 * 4]);
#pragma unroll
      for (int j = 0; j < 4; ++j) F4(&b[j][0]) = F4(&Bs[k4 * 4 + j][c0]);
#pragma unroll
      for (int i = 0; i < 4; ++i)
#pragma unroll
        for (int j = 0; j < 4; ++j)
#pragma unroll
          for (int c = 0; c < 4; ++c)
            acc[i][c] += a[i][j] * b[j][c];
    }
  }

  // epilogue
#pragma unroll
  for (int i = 0; i < 4; ++i) {
    const int gr = row0 + r0 + i;
    if (gr >= M) break;
    float* cp = &C[(long)gr * N + col0 + c0];
    if (ACC) {
      const float s = bias_or_scale[gr];
      float4 o = F4(cp);
      o.x += s * acc[i][0]; o.y += s * acc[i][1];
      o.z += s * acc[i][2]; o.w += s * acc[i][3];
      F4(cp) = o;
    } else {
      const float4 bv = F4C(&bias_or_scale[col0 + c0]);
      float4 o;
      o.x = acc[i][0] + bv.x; o.y = acc[i][1] + bv.y;
      o.z = acc[i][2] + bv.z; o.w = acc[i][3] + bv.w;
      F4(cp) = o;
    }
  }
}

// ---------------- edge kernels ----------------
__global__ __launch_bounds__(256)
void count_edges(const int* __restrict__ dst, const int* __restrict__ et,
                 int E, float* __restrict__ cnt) {
  const int e = blockIdx.x * 256 + threadIdx.x;
  if (e < E) atomicAdd(&cnt[et[e] * NN + dst[e]], 1.0f);
}

__global__ __launch_bounds__(256)
void inv_kernel(float* __restrict__ v, int n) {
  const int i = blockIdx.x * 256 + threadIdx.x;
  if (i < n) v[i] = 1.0f / fmaxf(v[i], 1.0f);
}

// one edge per 32 lanes; each lane handles one float4 of the 128-dim row
__global__ __launch_bounds__(256)
void scatter_rel(const float* __restrict__ X, const int* __restrict__ src,
                 const int* __restrict__ dst, const int* __restrict__ et,
                 int r, int E, float* __restrict__ agg) {
  const long gid = (long)blockIdx.x * 256 + threadIdx.x;
  const int e = (int)(gid >> 5);
  const int lane = (int)(gid & 31);
  if (e >= E) return;
  if (et[e] != r) return;
  const int s = src[e], d = dst[e];
  const float4 v = F4C(&X[(long)s * KD + lane * 4]);
  float* a = &agg[(long)d * KD + lane * 4];
  atomicAdd(a + 0, v.x);
  atomicAdd(a + 1, v.y);
  atomicAdd(a + 2, v.z);
  atomicAdd(a + 3, v.w);
}

__global__ __launch_bounds__(256)
void relu_kernel(float* __restrict__ v, int n4) {
  const int i = blockIdx.x * 256 + threadIdx.x;
  if (i < n4) {
    float4 x = F4(&v[i * 4]);
    x.x = fmaxf(x.x, 0.f); x.y = fmaxf(x.y, 0.f);
    x.z = fmaxf(x.z, 0.f); x.w = fmaxf(x.w, 0.f);
    F4(&v[i * 4]) = x;
  }
}

// ---------------- launch ----------------
extern "C" void kernel_launch(void* const* d_in, const int* in_sizes, int n_in,
                              void* d_out, int out_size, void* d_ws, size_t ws_size,
                              hipStream_t stream) {
  const float* x     = (const float*)d_in[0];
  const int*   ei    = (const int*)d_in[1];
  const int*   et    = (const int*)d_in[2];
  const float* W1    = (const float*)d_in[3];
  const float* root1 = (const float*)d_in[4];
  const float* b1    = (const float*)d_in[5];
  const float* W2    = (const float*)d_in[6];
  const float* root2 = (const float*)d_in[7];
  const float* b2    = (const float*)d_in[8];
  float* out = (float*)d_out;

  const int E = in_sizes[2];          // 800000
  const int* src  = ei;
  const int* dstv = ei + E;

  float* h   = (float*)d_ws;                    // NN*KD
  float* agg = h + (size_t)NN * KD;             // NN*KD
  float* inv = agg + (size_t)NN * KD;           // RR*NN

  // per-(relation,dst) counts -> inverse
  hipMemsetAsync(inv, 0, sizeof(float) * (size_t)RR * NN, stream);
  count_edges<<<(E + 255) / 256, 256, 0, stream>>>(dstv, et, E, inv);
  inv_kernel<<<(RR * NN + 255) / 256, 256, 0, stream>>>(inv, RR * NN);

  const int scatterBlocks = (int)(((long)E * 32 + 255) / 256);
  const dim3 g1((NN + 63) / 64, 2);   // N=128
  const dim3 g2((NN + 63) / 64, 1);   // N=64

  // ---- layer 1: h = relu(x@root1 + b1 + sum_r inv_r * (agg_r @ W1_r)) ----
  gemm_k128<false><<<g1, 256, 0, stream>>>(x, root1, h, b1, NN, 128);
  for (int r = 0; r < RR; ++r) {
    hipMemsetAsync(agg, 0, sizeof(float) * (size_t)NN * KD, stream);
    scatter_rel<<<scatterBlocks, 256, 0, stream>>>(x, src, dstv, et, r, E, agg);
    gemm_k128<true><<<g1, 256, 0, stream>>>(agg, W1 + (size_t)r * KD * 128, h,
                                            inv + (size_t)r * NN, NN, 128);
  }
  relu_kernel<<<(NN * KD / 4 + 255) / 256, 256, 0, stream>>>(h, NN * KD / 4);

  // ---- layer 2: out = h@root2 + b2 + sum_r inv_r * (agg_r @ W2_r) ----
  gemm_k128<false><<<g2, 256, 0, stream>>>(h, root2, out, b2, NN, 64);
  for (int r = 0; r < RR; ++r) {
    hipMemsetAsync(agg, 0, sizeof(float) * (size_t)NN * KD, stream);
    scatter_rel<<<scatterBlocks, 256, 0, stream>>>(h, src, dstv, et, r, E, agg);
    gemm_k128<true><<<g2, 256, 0, stream>>>(agg, W2 + (size_t)r * KD * 64, out,
                                            inv + (size_t)r * NN, NN, 64);
  }
}

// Round 2
// 674.301 us; speedup vs baseline: 5.1249x; 5.1249x over previous
//
#include <hip/hip_runtime.h>

constexpr int NN   = 50000;     // nodes
constexpr int KD   = 128;       // feature dim (per-chunk GEMM K)
constexpr int RR   = 8;         // relations
constexpr int NSEG = RR * NN;   // 400000 (relation, dst) segments

#define F4(p)  (*(float4*)(p))
#define F4C(p) (*(const float4*)(p))

__device__ __forceinline__ float bflo(unsigned u) { return __uint_as_float(u << 16); }
__device__ __forceinline__ float bfhi(unsigned u) { return __uint_as_float(u & 0xffff0000u); }
// pack two fp32 -> two bf16 (RNE) in one uint (a = low half, b = high half)
__device__ __forceinline__ unsigned pk_bf16(float a, float b) {
  unsigned ua = __float_as_uint(a), ub = __float_as_uint(b);
  ua = (ua + 0x7fffu + ((ua >> 16) & 1u)) >> 16;
  ub = (ub + 0x7fffu + ((ub >> 16) & 1u)) & 0xffff0000u;
  return (ua & 0xffffu) | ub;
}

// ---------------- structure build (once per call) ----------------
__global__ __launch_bounds__(256)
void count_edges(const int* __restrict__ dst, const int* __restrict__ et,
                 int E, int* __restrict__ cnt) {
  const int e = blockIdx.x * 256 + threadIdx.x;
  if (e < E) atomicAdd(&cnt[et[e] * NN + dst[e]], 1);
}

__global__ __launch_bounds__(256)
void alloc_segs(const int* __restrict__ cnt, int* __restrict__ cursor,
                int* __restrict__ segbase, int* __restrict__ fillpos) {
  const int s = blockIdx.x * 256 + threadIdx.x;
  if (s < NSEG) {
    const int base = atomicAdd(cursor, cnt[s]);  // wave-aggregated by compiler
    segbase[s] = base;
    fillpos[s] = base;
  }
}

__global__ __launch_bounds__(256)
void fill_edges(const int* __restrict__ src, const int* __restrict__ dst,
                const int* __restrict__ et, int E,
                int* __restrict__ fillpos, int* __restrict__ sortedSrc) {
  const int e = blockIdx.x * 256 + threadIdx.x;
  if (e < E) {
    const int seg = et[e] * NN + dst[e];
    const int pos = atomicAdd(&fillpos[seg], 1);
    sortedSrc[pos] = src[e];
  }
}

// ---------------- per-layer gather: agg[r][d][:] = mean of X rows (bf16) ----
// one 32-lane group per segment; lane owns 4 consecutive floats of the row
__global__ __launch_bounds__(256)
void gather_mean(const float* __restrict__ X, const int* __restrict__ sortedSrc,
                 const int* __restrict__ segbase, const int* __restrict__ cnt,
                 unsigned* __restrict__ agg /* bf16 pairs, [NSEG][KD/2] */) {
  const int g = blockIdx.x * 8 + (threadIdx.x >> 5);   // segment id = r*NN + d
  const int lane = threadIdx.x & 31;
  const int base = segbase[g];
  const int c = cnt[g];
  float4 acc = make_float4(0.f, 0.f, 0.f, 0.f);
  for (int i = 0; i < c; ++i) {
    const int s = sortedSrc[base + i];
    const float4 v = F4C(&X[(size_t)s * KD + lane * 4]);
    acc.x += v.x; acc.y += v.y; acc.z += v.z; acc.w += v.w;
  }
  const float sc = (c > 0) ? 1.0f / (float)c : 0.0f;   // fold mean; zeros if empty
  uint2 o;
  o.x = pk_bf16(acc.x * sc, acc.y * sc);
  o.y = pk_bf16(acc.z * sc, acc.w * sc);
  *(uint2*)(&agg[(size_t)g * (KD / 2) + lane * 2]) = o;
}

// ---------------- fused multi-chunk GEMM ----------------
// C[M,N] = sum_{c=0..7} bf16(agg_c)[M,128] @ W_c[128,N]  +  X[M,128] @ root[128,N] + bias
// BM=64, BN=64, BK=32, 256 threads, 4x4 register tile. grid = (ceil(M/64), N/64)
template<bool RELU>
__global__ __launch_bounds__(256)
void rgcn_gemm(const unsigned* __restrict__ agg, const float* __restrict__ X,
               const float* __restrict__ W, const float* __restrict__ root,
               const float* __restrict__ bias, float* __restrict__ C,
               int M, int N) {
  __shared__ float As[64][36];
  __shared__ float Bs[32][68];
  const int t = threadIdx.x;
  const int row0 = blockIdx.x * 64;
  const int col0 = blockIdx.y * 64;
  const int r0 = (t >> 4) * 4, c0 = (t & 15) * 4;

  float acc[4][4] = {};

  for (int ch = 0; ch < 9; ++ch) {
    const bool isAgg = (ch < 8);
    const unsigned* aP = agg + (size_t)ch * NN * (KD / 2);
    const float* bP = isAgg ? (W + (size_t)ch * KD * N) : root;

    for (int kt = 0; kt < 4; ++kt) {
      __syncthreads();
      // ---- stage A tile (64 rows x 32 k) ----
      {
        const int ar = t >> 2;             // 0..63
        const int ac = (t & 3) * 8;        // 0,8,16,24
        const int gr = row0 + ar;
        if (isAgg) {
          uint4 v = make_uint4(0u, 0u, 0u, 0u);
          if (gr < M) v = *(const uint4*)(aP + (size_t)gr * (KD / 2) + (kt * 32 + ac) / 2);
          As[ar][ac + 0] = bflo(v.x); As[ar][ac + 1] = bfhi(v.x);
          As[ar][ac + 2] = bflo(v.y); As[ar][ac + 3] = bfhi(v.y);
          As[ar][ac + 4] = bflo(v.z); As[ar][ac + 5] = bfhi(v.z);
          As[ar][ac + 6] = bflo(v.w); As[ar][ac + 7] = bfhi(v.w);
        } else {
          float4 v0 = make_float4(0.f, 0.f, 0.f, 0.f), v1 = v0;
          if (gr < M) {
            v0 = F4C(&X[(size_t)gr * KD + kt * 32 + ac]);
            v1 = F4C(&X[(size_t)gr * KD + kt * 32 + ac + 4]);
          }
          As[ar][ac + 0] = v0.x; As[ar][ac + 1] = v0.y;
          As[ar][ac + 2] = v0.z; As[ar][ac + 3] = v0.w;
          As[ar][ac + 4] = v1.x; As[ar][ac + 5] = v1.y;
          As[ar][ac + 6] = v1.z; As[ar][ac + 7] = v1.w;
        }
      }
      // ---- stage B tile (32 k x 64 cols) ----
      {
        const int bc = (t & 15) * 4;
        const int br = t >> 4;             // 0..15
#pragma unroll
        for (int hh = 0; hh < 2; ++hh) {
          const int k = br + hh * 16;
          F4(&Bs[k][bc]) = F4C(&bP[(size_t)(kt * 32 + k) * N + col0 + bc]);
        }
      }
      __syncthreads();
      // ---- MAC ----
#pragma unroll
      for (int k4 = 0; k4 < 8; ++k4) {
        float a[4][4], b[4][4];
#pragma unroll
        for (int i = 0; i < 4; ++i) F4(&a[i][0]) = F4(&As[r0 + i][k4 * 4]);
#pragma unroll
        for (int j = 0; j < 4; ++j) F4(&b[j][0]) = F4(&Bs[k4 * 4 + j][c0]);
#pragma unroll
        for (int i = 0; i < 4; ++i)
#pragma unroll
          for (int j = 0; j < 4; ++j)
#pragma unroll
            for (int cc = 0; cc < 4; ++cc)
              acc[i][cc] += a[i][j] * b[j][cc];
      }
    }
  }

  // ---- epilogue: + bias (, relu) ----
  const float4 bv = F4C(&bias[col0 + c0]);
#pragma unroll
  for (int i = 0; i < 4; ++i) {
    const int gr = row0 + r0 + i;
    if (gr < M) {
      float4 o;
      o.x = acc[i][0] + bv.x; o.y = acc[i][1] + bv.y;
      o.z = acc[i][2] + bv.z; o.w = acc[i][3] + bv.w;
      if (RELU) {
        o.x = fmaxf(o.x, 0.f); o.y = fmaxf(o.y, 0.f);
        o.z = fmaxf(o.z, 0.f); o.w = fmaxf(o.w, 0.f);
      }
      F4(&C[(size_t)gr * N + col0 + c0]) = o;
    }
  }
}

// ---------------- launch ----------------
extern "C" void kernel_launch(void* const* d_in, const int* in_sizes, int n_in,
                              void* d_out, int out_size, void* d_ws, size_t ws_size,
                              hipStream_t stream) {
  const float* x     = (const float*)d_in[0];
  const int*   ei    = (const int*)d_in[1];
  const int*   et    = (const int*)d_in[2];
  const float* W1    = (const float*)d_in[3];
  const float* root1 = (const float*)d_in[4];
  const float* b1    = (const float*)d_in[5];
  const float* W2    = (const float*)d_in[6];
  const float* root2 = (const float*)d_in[7];
  const float* b2    = (const float*)d_in[8];
  float* out = (float*)d_out;

  const int E = in_sizes[2];          // 800000
  const int* src  = ei;
  const int* dstv = ei + E;

  // workspace layout (~136 MB total)
  char* ws = (char*)d_ws;
  float*    h       = (float*)ws;                        // 25.6 MB
  unsigned* agg     = (unsigned*)(ws + 25600000);        // bf16 agg, 102.4 MB
  int*      cnt     = (int*)(ws + 128000000);            // NSEG ints
  int*      cursor  = cnt + NSEG;                        // 16 ints
  int*      segbase = cursor + 16;                       // NSEG
  int*      fillpos = segbase + NSEG;                    // NSEG
  int*      sortedSrc = fillpos + NSEG;                  // E

  // build segment structure (cnt + cursor zeroed together)
  hipMemsetAsync(cnt, 0, sizeof(int) * (size_t)(NSEG + 16), stream);
  count_edges<<<(E + 255) / 256, 256, 0, stream>>>(dstv, et, E, cnt);
  alloc_segs<<<(NSEG + 255) / 256, 256, 0, stream>>>(cnt, cursor, segbase, fillpos);
  fill_edges<<<(E + 255) / 256, 256, 0, stream>>>(src, dstv, et, E, fillpos, sortedSrc);

  const int gatherBlocks = NSEG / 8;   // 50000, exact
  const int mBlocks = (NN + 63) / 64;  // 782

  // layer 1: h = relu(sum_r mean_r(x) @ W1_r + x @ root1 + b1)
  gather_mean<<<gatherBlocks, 256, 0, stream>>>(x, sortedSrc, segbase, cnt, agg);
  rgcn_gemm<true><<<dim3(mBlocks, 2), 256, 0, stream>>>(agg, x, W1, root1, b1, h, NN, 128);

  // layer 2: out = sum_r mean_r(h) @ W2_r + h @ root2 + b2
  gather_mean<<<gatherBlocks, 256, 0, stream>>>(h, sortedSrc, segbase, cnt, agg);
  rgcn_gemm<false><<<dim3(mBlocks, 1), 256, 0, stream>>>(agg, h, W2, root2, b2, out, NN, 64);
}

// Round 3
// 348.210 us; speedup vs baseline: 9.9243x; 1.9365x over previous
//
#include <hip/hip_runtime.h>

constexpr int NN   = 50000;
constexpr int PADN = 50048;       // 391*128, padded rows
constexpr int KD   = 128;
constexpr int RR   = 8;
constexpr int NSEG = RR * NN;     // 400000

typedef __attribute__((ext_vector_type(8))) short short8;
typedef __attribute__((ext_vector_type(4))) float f32x4;

__device__ __forceinline__ float bflo(unsigned u){ return __uint_as_float(u << 16); }
__device__ __forceinline__ float bfhi(unsigned u){ return __uint_as_float(u & 0xffff0000u); }
__device__ __forceinline__ unsigned pk_bf16(float a, float b){
  unsigned ua = __float_as_uint(a), ub = __float_as_uint(b);
  ua = (ua + 0x7fffu + ((ua >> 16) & 1u)) >> 16;
  ub = (ub + 0x7fffu + ((ub >> 16) & 1u)) & 0xffff0000u;
  return (ua & 0xffffu) | ub;
}
__device__ __forceinline__ unsigned short bf1(float a){
  unsigned ua = __float_as_uint(a);
  return (unsigned short)((ua + 0x7fffu + ((ua >> 16) & 1u)) >> 16);
}

// ---------------- structure build ----------------
__global__ __launch_bounds__(256)
void count_edges(const int* __restrict__ dst, const int* __restrict__ et,
                 int E, int* __restrict__ cnt) {
  const int e = blockIdx.x * 256 + threadIdx.x;
  if (e < E) atomicAdd(&cnt[et[e] * NN + dst[e]], 1);
}

// one atomic per wave: in-wave exclusive scan of counts
__global__ __launch_bounds__(256)
void alloc_segs(const int* __restrict__ cnt, int* __restrict__ cursor,
                int* __restrict__ fillpos) {
  const int s = blockIdx.x * 256 + threadIdx.x;
  const int c = (s < NSEG) ? cnt[s] : 0;
  int sc = c;
#pragma unroll
  for (int o = 1; o < 64; o <<= 1) {
    int v = __shfl_up(sc, o);
    if ((threadIdx.x & 63) >= o) sc += v;
  }
  int wb = 0;
  if ((threadIdx.x & 63) == 63) wb = atomicAdd(cursor, sc);
  wb = __shfl(wb, 63);
  if (s < NSEG) fillpos[s] = wb + sc - c;   // exclusive base
}

__global__ __launch_bounds__(256)
void fill_edges(const int* __restrict__ src, const int* __restrict__ dst,
                const int* __restrict__ et, int E,
                int* __restrict__ fillpos, int* __restrict__ srt) {
  const int e = blockIdx.x * 256 + threadIdx.x;
  if (e < E) {
    const int seg = et[e] * NN + dst[e];
    srt[atomicAdd(&fillpos[seg], 1)] = src[e];
  }
}

// ---------------- conversions ----------------
__global__ __launch_bounds__(256)
void convert_x(const float* __restrict__ x, unsigned* __restrict__ xb) {
  const int idx = blockIdx.x * 256 + threadIdx.x;   // one per 8 elems
  if (idx >= PADN * 16) return;
  const int row = idx >> 4, o = (idx & 15) * 8;
  uint4 v = make_uint4(0u, 0u, 0u, 0u);
  if (row < NN) {
    float4 a = *(const float4*)&x[(size_t)row * KD + o];
    float4 b = *(const float4*)&x[(size_t)row * KD + o + 4];
    v.x = pk_bf16(a.x, a.y); v.y = pk_bf16(a.z, a.w);
    v.z = pk_bf16(b.x, b.y); v.w = pk_bf16(b.z, b.w);
  }
  *(uint4*)&xb[(size_t)idx * 4] = v;
}

// Wt[9][Nw][128] bf16  <-  W[8][128][Nw] fp32 (transposed), ch 8 = root[128][Nw]
__global__ __launch_bounds__(256)
void prep_w(const float* __restrict__ W, const float* __restrict__ root,
            unsigned short* __restrict__ Wt, int Nw) {
  const int idx = blockIdx.x * 256 + threadIdx.x;
  if (idx >= 9 * Nw * KD) return;
  const int k = idx & 127;
  const int n = (idx >> 7) % Nw;
  const int ch = idx / (Nw * KD);
  const float v = (ch < 8) ? W[((size_t)ch * KD + k) * Nw + n] : root[(size_t)k * Nw + n];
  Wt[idx] = bf1(v);
}

// ---------------- gather: agg[r][d][:] = mean of bf16 X rows ----------------
// 16 lanes per segment, lane owns 8 consecutive bf16 of the 128-dim row
__global__ __launch_bounds__(256)
void gather_mean(const unsigned* __restrict__ Xb,         // [PADN][64] uint
                 const int* __restrict__ srt,
                 const int* __restrict__ segend, const int* __restrict__ cnt,
                 unsigned* __restrict__ agg) {            // [8][PADN][64] uint
  const int g = blockIdx.x * 16 + (threadIdx.x >> 4);
  const int lane = threadIdx.x & 15;
  const int c = cnt[g];
  const int base = segend[g] - c;
  float acc[8] = {};
  for (int i = 0; i < c; ++i) {
    const int s = srt[base + i];
    uint4 v = *(const uint4*)&Xb[(size_t)s * 64 + lane * 4];
    acc[0] += bflo(v.x); acc[1] += bfhi(v.x);
    acc[2] += bflo(v.y); acc[3] += bfhi(v.y);
    acc[4] += bflo(v.z); acc[5] += bfhi(v.z);
    acc[6] += bflo(v.w); acc[7] += bfhi(v.w);
  }
  const float sc = (c > 0) ? 1.0f / (float)c : 0.0f;
  uint4 o;
  o.x = pk_bf16(acc[0] * sc, acc[1] * sc); o.y = pk_bf16(acc[2] * sc, acc[3] * sc);
  o.z = pk_bf16(acc[4] * sc, acc[5] * sc); o.w = pk_bf16(acc[6] * sc, acc[7] * sc);
  const int r = g / NN, d = g - r * NN;
  *(uint4*)&agg[((size_t)r * PADN + d) * 64 + lane * 4] = o;
}

// ---------------- MFMA GEMM ----------------
// C[M,BN] = sum_{ch<8} agg_ch[M,128] @ Wt_ch^T + xrow[M,128] @ Wt_8^T (+bias)(relu)
// BM=128, BK=64, 256 threads = 4 waves. LDS XOR-swizzled (byte ^= (row&7)<<4).
template<int BN, bool RELU, bool OUTBF16>
__global__ __launch_bounds__(256)
void rgcn_gemm_mfma(const unsigned short* __restrict__ agg,   // [8][PADN][128] bf16
                    const unsigned short* __restrict__ xrow,  // [PADN][128] bf16
                    const unsigned short* __restrict__ Wt,    // [9][BN][128] bf16
                    const float* __restrict__ bias,
                    void* __restrict__ Cout) {
  constexpr int WM = (BN == 128) ? 64 : 32;   // wave M-tile
  constexpr int MF = WM / 16;                 // 4 or 2 m-fragments
  constexpr int NF = 4;                       // WN = 64 always
  constexpr int WAVES_N = BN / 64;

  __shared__ uint4 ldsv[(128 * 128 + BN * 128) / 16];
  char* As = (char*)ldsv;                 // [128][128B] swizzled
  char* Bs = (char*)ldsv + 128 * 128;     // [BN][128B]  swizzled

  const int t = threadIdx.x;
  const int l = t & 63;
  const int w = t >> 6;
  const int wr = w / WAVES_N;
  const int wc = w % WAVES_N;
  const int row0 = blockIdx.x * 128;
  const int l15 = l & 15, lq = l >> 4;

  f32x4 acc[MF][NF];
#pragma unroll
  for (int mi = 0; mi < MF; ++mi)
#pragma unroll
    for (int ni = 0; ni < NF; ++ni) acc[mi][ni] = (f32x4){0.f, 0.f, 0.f, 0.f};

  for (int ch = 0; ch < 9; ++ch) {
    const unsigned short* aP = (ch < 8) ? (agg + (size_t)ch * PADN * KD) : xrow;
    const unsigned short* bP = Wt + (size_t)ch * BN * KD;
#pragma unroll
    for (int kt = 0; kt < 2; ++kt) {
      __syncthreads();
      // stage A: 128 rows x 64 bf16 (1024 x 16B slots)
#pragma unroll
      for (int i = 0; i < 4; ++i) {
        const int s = t + i * 256;
        const int r = s >> 3, c16 = s & 7;
        uint4 v = *(const uint4*)(aP + (size_t)(row0 + r) * KD + kt * 64 + c16 * 8);
        *(uint4*)(As + r * 128 + ((c16 ^ (r & 7)) * 16)) = v;
      }
      // stage B: BN rows x 64 bf16
#pragma unroll
      for (int i = 0; i < BN / 32; ++i) {
        const int s = t + i * 256;
        const int r = s >> 3, c16 = s & 7;
        uint4 v = *(const uint4*)(bP + (size_t)r * KD + kt * 64 + c16 * 8);
        *(uint4*)(Bs + r * 128 + ((c16 ^ (r & 7)) * 16)) = v;
      }
      __syncthreads();
#pragma unroll
      for (int ks = 0; ks < 2; ++ks) {
        short8 bfr[NF];
#pragma unroll
        for (int ni = 0; ni < NF; ++ni) {
          const int br = wc * 64 + ni * 16 + l15;
          bfr[ni] = *(const short8*)(Bs + br * 128 + (((ks * 4 + lq) ^ (br & 7)) * 16));
        }
#pragma unroll
        for (int mi = 0; mi < MF; ++mi) {
          const int ar = wr * WM + mi * 16 + l15;
          short8 af = *(const short8*)(As + ar * 128 + (((ks * 4 + lq) ^ (ar & 7)) * 16));
#pragma unroll
          for (int ni = 0; ni < NF; ++ni)
            acc[mi][ni] = __builtin_amdgcn_mfma_f32_16x16x32_bf16(af, bfr[ni], acc[mi][ni], 0, 0, 0);
        }
      }
    }
  }
  // epilogue: C row = (lq*4+q), col = l15 within each 16x16 fragment
#pragma unroll
  for (int ni = 0; ni < NF; ++ni) {
    const int col = wc * 64 + ni * 16 + l15;
    const float bv = bias[col];
#pragma unroll
    for (int mi = 0; mi < MF; ++mi) {
#pragma unroll
      for (int q = 0; q < 4; ++q) {
        const int grow = row0 + wr * WM + mi * 16 + lq * 4 + q;
        if (grow < NN) {
          float v = acc[mi][ni][q] + bv;
          if (RELU) v = fmaxf(v, 0.f);
          if (OUTBF16) ((unsigned short*)Cout)[(size_t)grow * BN + col] = bf1(v);
          else         ((float*)Cout)[(size_t)grow * BN + col] = v;
        }
      }
    }
  }
}

// ---------------- launch ----------------
extern "C" void kernel_launch(void* const* d_in, const int* in_sizes, int n_in,
                              void* d_out, int out_size, void* d_ws, size_t ws_size,
                              hipStream_t stream) {
  const float* x     = (const float*)d_in[0];
  const int*   ei    = (const int*)d_in[1];
  const int*   et    = (const int*)d_in[2];
  const float* W1    = (const float*)d_in[3];
  const float* root1 = (const float*)d_in[4];
  const float* b1    = (const float*)d_in[5];
  const float* W2    = (const float*)d_in[6];
  const float* root2 = (const float*)d_in[7];
  const float* b2    = (const float*)d_in[8];
  float* out = (float*)d_out;

  const int E = in_sizes[2];
  const int* src  = ei;
  const int* dstv = ei + E;

  // workspace layout (~135 MB, 16B-aligned blocks)
  char* ws = (char*)d_ws;
  unsigned short* xb  = (unsigned short*)ws;                 // 12,812,288 B
  unsigned short* hb  = (unsigned short*)(ws + 12812288);    // 12,812,288 B
  unsigned short* agg = (unsigned short*)(ws + 25624576);    // 102,498,304 B
  unsigned short* Wt1 = (unsigned short*)(ws + 128122880);   //    294,912 B
  unsigned short* Wt2 = (unsigned short*)(ws + 128417792);   //    147,456 B
  int* cnt     = (int*)(ws + 128565248);                     //  1,600,000 B
  int* cursor  = (int*)(ws + 130165248);                     //         64 B
  int* fillpos = (int*)(ws + 130165312);                     //  1,600,000 B
  int* srt     = (int*)(ws + 131765312);                     //  3,200,000 B

  hipMemsetAsync(cnt, 0, 1600064, stream);  // cnt + cursor
  count_edges<<<(E + 255) / 256, 256, 0, stream>>>(dstv, et, E, cnt);
  alloc_segs<<<(NSEG + 255) / 256, 256, 0, stream>>>(cnt, cursor, fillpos);
  fill_edges<<<(E + 255) / 256, 256, 0, stream>>>(src, dstv, et, E, fillpos, srt);
  // after fill: fillpos[s] = segment end

  convert_x<<<PADN * 16 / 256, 256, 0, stream>>>(x, (unsigned*)xb);
  prep_w<<<(9 * 128 * KD + 255) / 256, 256, 0, stream>>>(W1, root1, Wt1, 128);
  prep_w<<<(9 * 64 * KD + 255) / 256, 256, 0, stream>>>(W2, root2, Wt2, 64);

  const int gatherBlocks = NSEG / 16;   // 25000
  const int mBlocks = PADN / 128;       // 391

  // layer 1
  gather_mean<<<gatherBlocks, 256, 0, stream>>>((const unsigned*)xb, srt, fillpos, cnt, (unsigned*)agg);
  rgcn_gemm_mfma<128, true, true><<<mBlocks, 256, 0, stream>>>(agg, xb, Wt1, b1, hb);

  // layer 2
  gather_mean<<<gatherBlocks, 256, 0, stream>>>((const unsigned*)hb, srt, fillpos, cnt, (unsigned*)agg);
  rgcn_gemm_mfma<64, false, false><<<mBlocks, 256, 0, stream>>>(agg, hb, Wt2, b2, out);
}

// Round 4
// 282.751 us; speedup vs baseline: 12.2219x; 1.2315x over previous
//
#include <hip/hip_runtime.h>

constexpr int NN   = 50000;
constexpr int PADN = 50048;       // 391*128, padded rows
constexpr int KD   = 128;
constexpr int RR   = 8;
constexpr int NSEG = RR * NN;     // 400000
constexpr int NBLK = 196;         // scan blocks: 196*2048 = 401408 >= NSEG
constexpr int PADSEG = NBLK * 2048;

typedef __attribute__((ext_vector_type(8))) short short8;
typedef __attribute__((ext_vector_type(4))) float f32x4;

__device__ __forceinline__ float bflo(unsigned u){ return __uint_as_float(u << 16); }
__device__ __forceinline__ float bfhi(unsigned u){ return __uint_as_float(u & 0xffff0000u); }
__device__ __forceinline__ unsigned pk_bf16(float a, float b){
  unsigned ua = __float_as_uint(a), ub = __float_as_uint(b);
  ua = (ua + 0x7fffu + ((ua >> 16) & 1u)) >> 16;
  ub = (ub + 0x7fffu + ((ub >> 16) & 1u)) & 0xffff0000u;
  return (ua & 0xffffu) | ub;
}
__device__ __forceinline__ unsigned short bf1(float a){
  unsigned ua = __float_as_uint(a);
  return (unsigned short)((ua + 0x7fffu + ((ua >> 16) & 1u)) >> 16);
}

// ---------------- structure build ----------------
__global__ __launch_bounds__(256)
void count_edges(const int* __restrict__ dst, const int* __restrict__ et,
                 int E, int* __restrict__ cnt) {
  const int e = blockIdx.x * 256 + threadIdx.x;
  if (e < E) atomicAdd(&cnt[et[e] * NN + dst[e]], 1);
}

// hierarchical exclusive scan, stage 1: per-block (2048 segs) scan, no atomics
__global__ __launch_bounds__(256)
void scan_block(const int* __restrict__ cnt, int* __restrict__ fillpos,
                int* __restrict__ blkSum) {
  const int t = threadIdx.x;
  const int base = blockIdx.x * 2048 + t * 8;
  const int4 a = *(const int4*)&cnt[base];
  const int4 b = *(const int4*)&cnt[base + 4];
  const int s8[8] = {a.x, a.y, a.z, a.w, b.x, b.y, b.z, b.w};
  int tsum = 0;
#pragma unroll
  for (int i = 0; i < 8; ++i) tsum += s8[i];
  // wave inclusive scan of per-thread sums
  int inc = tsum;
#pragma unroll
  for (int o = 1; o < 64; o <<= 1) {
    int v = __shfl_up(inc, o);
    if ((t & 63) >= o) inc += v;
  }
  __shared__ int wsum[4];
  if ((t & 63) == 63) wsum[t >> 6] = inc;
  __syncthreads();
  int wpre = 0;
#pragma unroll
  for (int w = 0; w < 4; ++w) if (w < (t >> 6)) wpre += wsum[w];
  int run = wpre + inc - tsum;      // block-relative exclusive base
  int o8[8];
#pragma unroll
  for (int i = 0; i < 8; ++i) { o8[i] = run; run += s8[i]; }
  *(int4*)&fillpos[base]     = make_int4(o8[0], o8[1], o8[2], o8[3]);
  *(int4*)&fillpos[base + 4] = make_int4(o8[4], o8[5], o8[6], o8[7]);
  if (t == 255) blkSum[blockIdx.x] = wpre + inc;
}

// stage 2: single block scans the 196 block sums -> exclusive offsets
__global__ __launch_bounds__(256)
void scan_tops(int* __restrict__ blkSum) {
  const int t = threadIdx.x;
  const int v = (t < NBLK) ? blkSum[t] : 0;
  int inc = v;
#pragma unroll
  for (int o = 1; o < 64; o <<= 1) {
    int u = __shfl_up(inc, o);
    if ((t & 63) >= o) inc += u;
  }
  __shared__ int wsum[4];
  if ((t & 63) == 63) wsum[t >> 6] = inc;
  __syncthreads();
  int wpre = 0;
#pragma unroll
  for (int w = 0; w < 4; ++w) if (w < (t >> 6)) wpre += wsum[w];
  if (t < NBLK) blkSum[t] = wpre + inc - v;   // exclusive
}

// stage 3: add block offsets
__global__ __launch_bounds__(256)
void scan_apply(int* __restrict__ fillpos, const int* __restrict__ blkSum) {
  const int base = blockIdx.x * 2048 + threadIdx.x * 8;
  const int off = blkSum[blockIdx.x];
  int4 a = *(int4*)&fillpos[base];
  int4 b = *(int4*)&fillpos[base + 4];
  a.x += off; a.y += off; a.z += off; a.w += off;
  b.x += off; b.y += off; b.z += off; b.w += off;
  *(int4*)&fillpos[base]     = a;
  *(int4*)&fillpos[base + 4] = b;
}

__global__ __launch_bounds__(256)
void fill_edges(const int* __restrict__ src, const int* __restrict__ dst,
                const int* __restrict__ et, int E,
                int* __restrict__ fillpos, int* __restrict__ srt) {
  const int e = blockIdx.x * 256 + threadIdx.x;
  if (e < E) {
    const int seg = et[e] * NN + dst[e];
    srt[atomicAdd(&fillpos[seg], 1)] = src[e];
  }
}

// ---------------- conversions ----------------
__global__ __launch_bounds__(256)
void convert_x(const float* __restrict__ x, unsigned* __restrict__ xb) {
  const int idx = blockIdx.x * 256 + threadIdx.x;   // one per 8 elems
  if (idx >= PADN * 16) return;
  const int row = idx >> 4, o = (idx & 15) * 8;
  uint4 v = make_uint4(0u, 0u, 0u, 0u);
  if (row < NN) {
    float4 a = *(const float4*)&x[(size_t)row * KD + o];
    float4 b = *(const float4*)&x[(size_t)row * KD + o + 4];
    v.x = pk_bf16(a.x, a.y); v.y = pk_bf16(a.z, a.w);
    v.z = pk_bf16(b.x, b.y); v.w = pk_bf16(b.z, b.w);
  }
  *(uint4*)&xb[(size_t)idx * 4] = v;
}

// Wt[9][Nw][128] bf16  <-  W[8][128][Nw] fp32 (transposed), ch 8 = root[128][Nw]
__global__ __launch_bounds__(256)
void prep_w(const float* __restrict__ W, const float* __restrict__ root,
            unsigned short* __restrict__ Wt, int Nw) {
  const int idx = blockIdx.x * 256 + threadIdx.x;
  if (idx >= 9 * Nw * KD) return;
  const int k = idx & 127;
  const int n = (idx >> 7) % Nw;
  const int ch = idx / (Nw * KD);
  const float v = (ch < 8) ? W[((size_t)ch * KD + k) * Nw + n] : root[(size_t)k * Nw + n];
  Wt[idx] = bf1(v);
}

// ---------------- gather: agg[r][d][:] = mean of bf16 X rows ----------------
// 16 lanes per segment, lane owns 8 consecutive bf16 of the 128-dim row
__global__ __launch_bounds__(256)
void gather_mean(const unsigned* __restrict__ Xb,         // [PADN][64] uint
                 const int* __restrict__ srt,
                 const int* __restrict__ segend, const int* __restrict__ cnt,
                 unsigned* __restrict__ agg) {            // [8][PADN][64] uint
  const int g = blockIdx.x * 16 + (threadIdx.x >> 4);
  const int lane = threadIdx.x & 15;
  const int c = cnt[g];
  const int base = segend[g] - c;
  float acc[8] = {};
  for (int i = 0; i < c; ++i) {
    const int s = srt[base + i];
    uint4 v = *(const uint4*)&Xb[(size_t)s * 64 + lane * 4];
    acc[0] += bflo(v.x); acc[1] += bfhi(v.x);
    acc[2] += bflo(v.y); acc[3] += bfhi(v.y);
    acc[4] += bflo(v.z); acc[5] += bfhi(v.z);
    acc[6] += bflo(v.w); acc[7] += bfhi(v.w);
  }
  const float sc = (c > 0) ? 1.0f / (float)c : 0.0f;
  uint4 o;
  o.x = pk_bf16(acc[0] * sc, acc[1] * sc); o.y = pk_bf16(acc[2] * sc, acc[3] * sc);
  o.z = pk_bf16(acc[4] * sc, acc[5] * sc); o.w = pk_bf16(acc[6] * sc, acc[7] * sc);
  const int r = g / NN, d = g - r * NN;
  *(uint4*)&agg[((size_t)r * PADN + d) * 64 + lane * 4] = o;
}

// ---------------- MFMA GEMM ----------------
// C[M,BN] = sum_{ch<8} agg_ch[M,128] @ Wt_ch^T + xrow[M,128] @ Wt_8^T (+bias)(relu)
// BM=128, BK=64, 256 threads = 4 waves. LDS XOR-swizzled (byte ^= (row&7)<<4).
template<int BN, bool RELU, bool OUTBF16>
__global__ __launch_bounds__(256)
void rgcn_gemm_mfma(const unsigned short* __restrict__ agg,   // [8][PADN][128] bf16
                    const unsigned short* __restrict__ xrow,  // [PADN][128] bf16
                    const unsigned short* __restrict__ Wt,    // [9][BN][128] bf16
                    const float* __restrict__ bias,
                    void* __restrict__ Cout) {
  constexpr int WM = (BN == 128) ? 64 : 32;   // wave M-tile
  constexpr int MF = WM / 16;                 // 4 or 2 m-fragments
  constexpr int NF = 4;                       // WN = 64 always
  constexpr int WAVES_N = BN / 64;

  __shared__ uint4 ldsv[(128 * 128 + BN * 128) / 16];
  char* As = (char*)ldsv;                 // [128][128B] swizzled
  char* Bs = (char*)ldsv + 128 * 128;     // [BN][128B]  swizzled

  const int t = threadIdx.x;
  const int l = t & 63;
  const int w = t >> 6;
  const int wr = w / WAVES_N;
  const int wc = w % WAVES_N;
  const int row0 = blockIdx.x * 128;
  const int l15 = l & 15, lq = l >> 4;

  f32x4 acc[MF][NF];
#pragma unroll
  for (int mi = 0; mi < MF; ++mi)
#pragma unroll
    for (int ni = 0; ni < NF; ++ni) acc[mi][ni] = (f32x4){0.f, 0.f, 0.f, 0.f};

  for (int ch = 0; ch < 9; ++ch) {
    const unsigned short* aP = (ch < 8) ? (agg + (size_t)ch * PADN * KD) : xrow;
    const unsigned short* bP = Wt + (size_t)ch * BN * KD;
#pragma unroll
    for (int kt = 0; kt < 2; ++kt) {
      __syncthreads();
      // stage A: 128 rows x 64 bf16 (1024 x 16B slots)
#pragma unroll
      for (int i = 0; i < 4; ++i) {
        const int s = t + i * 256;
        const int r = s >> 3, c16 = s & 7;
        uint4 v = *(const uint4*)(aP + (size_t)(row0 + r) * KD + kt * 64 + c16 * 8);
        *(uint4*)(As + r * 128 + ((c16 ^ (r & 7)) * 16)) = v;
      }
      // stage B: BN rows x 64 bf16
#pragma unroll
      for (int i = 0; i < BN / 32; ++i) {
        const int s = t + i * 256;
        const int r = s >> 3, c16 = s & 7;
        uint4 v = *(const uint4*)(bP + (size_t)r * KD + kt * 64 + c16 * 8);
        *(uint4*)(Bs + r * 128 + ((c16 ^ (r & 7)) * 16)) = v;
      }
      __syncthreads();
#pragma unroll
      for (int ks = 0; ks < 2; ++ks) {
        short8 bfr[NF];
#pragma unroll
        for (int ni = 0; ni < NF; ++ni) {
          const int br = wc * 64 + ni * 16 + l15;
          bfr[ni] = *(const short8*)(Bs + br * 128 + (((ks * 4 + lq) ^ (br & 7)) * 16));
        }
#pragma unroll
        for (int mi = 0; mi < MF; ++mi) {
          const int ar = wr * WM + mi * 16 + l15;
          short8 af = *(const short8*)(As + ar * 128 + (((ks * 4 + lq) ^ (ar & 7)) * 16));
#pragma unroll
          for (int ni = 0; ni < NF; ++ni)
            acc[mi][ni] = __builtin_amdgcn_mfma_f32_16x16x32_bf16(af, bfr[ni], acc[mi][ni], 0, 0, 0);
        }
      }
    }
  }
  // epilogue: C row = (lq*4+q), col = l15 within each 16x16 fragment
#pragma unroll
  for (int ni = 0; ni < NF; ++ni) {
    const int col = wc * 64 + ni * 16 + l15;
    const float bv = bias[col];
#pragma unroll
    for (int mi = 0; mi < MF; ++mi) {
#pragma unroll
      for (int q = 0; q < 4; ++q) {
        const int grow = row0 + wr * WM + mi * 16 + lq * 4 + q;
        if (grow < NN) {
          float v = acc[mi][ni][q] + bv;
          if (RELU) v = fmaxf(v, 0.f);
          if (OUTBF16) ((unsigned short*)Cout)[(size_t)grow * BN + col] = bf1(v);
          else         ((float*)Cout)[(size_t)grow * BN + col] = v;
        }
      }
    }
  }
}

// ---------------- launch ----------------
extern "C" void kernel_launch(void* const* d_in, const int* in_sizes, int n_in,
                              void* d_out, int out_size, void* d_ws, size_t ws_size,
                              hipStream_t stream) {
  const float* x     = (const float*)d_in[0];
  const int*   ei    = (const int*)d_in[1];
  const int*   et    = (const int*)d_in[2];
  const float* W1    = (const float*)d_in[3];
  const float* root1 = (const float*)d_in[4];
  const float* b1    = (const float*)d_in[5];
  const float* W2    = (const float*)d_in[6];
  const float* root2 = (const float*)d_in[7];
  const float* b2    = (const float*)d_in[8];
  float* out = (float*)d_out;

  const int E = in_sizes[2];
  const int* src  = ei;
  const int* dstv = ei + E;

  // workspace layout (~135 MB, 16B-aligned blocks)
  char* ws = (char*)d_ws;
  unsigned short* xb  = (unsigned short*)ws;                 // 12,812,288 B
  unsigned short* hb  = (unsigned short*)(ws + 12812288);    // 12,812,288 B
  unsigned short* agg = (unsigned short*)(ws + 25624576);    // 102,498,304 B
  unsigned short* Wt1 = (unsigned short*)(ws + 128122880);   //    294,912 B
  unsigned short* Wt2 = (unsigned short*)(ws + 128417792);   //    147,456 B
  int* cnt     = (int*)(ws + 128565248);                     // PADSEG*4 = 1,605,632 B
  int* fillpos = (int*)(ws + 130170880);                     // PADSEG*4 = 1,605,632 B
  int* blkSum  = (int*)(ws + 131776512);                     //      1,024 B
  int* srt     = (int*)(ws + 131777536);                     //  3,200,000 B (ends 134,977,536)

  // build segment structure: count -> scan (no global atomics) -> fill
  hipMemsetAsync(cnt, 0, sizeof(int) * (size_t)PADSEG, stream);
  count_edges<<<(E + 255) / 256, 256, 0, stream>>>(dstv, et, E, cnt);
  scan_block<<<NBLK, 256, 0, stream>>>(cnt, fillpos, blkSum);
  scan_tops<<<1, 256, 0, stream>>>(blkSum);
  scan_apply<<<NBLK, 256, 0, stream>>>(fillpos, blkSum);
  fill_edges<<<(E + 255) / 256, 256, 0, stream>>>(src, dstv, et, E, fillpos, srt);
  // after fill: fillpos[s] = segment end

  convert_x<<<PADN * 16 / 256, 256, 0, stream>>>(x, (unsigned*)xb);
  prep_w<<<(9 * 128 * KD + 255) / 256, 256, 0, stream>>>(W1, root1, Wt1, 128);
  prep_w<<<(9 * 64 * KD + 255) / 256, 256, 0, stream>>>(W2, root2, Wt2, 64);

  const int gatherBlocks = NSEG / 16;   // 25000
  const int mBlocks = PADN / 128;       // 391

  // layer 1
  gather_mean<<<gatherBlocks, 256, 0, stream>>>((const unsigned*)xb, srt, fillpos, cnt, (unsigned*)agg);
  rgcn_gemm_mfma<128, true, true><<<mBlocks, 256, 0, stream>>>(agg, xb, Wt1, b1, hb);

  // layer 2
  gather_mean<<<gatherBlocks, 256, 0, stream>>>((const unsigned*)hb, srt, fillpos, cnt, (unsigned*)agg);
  rgcn_gemm_mfma<64, false, false><<<mBlocks, 256, 0, stream>>>(agg, hb, Wt2, b2, out);
}